// Round 10
// baseline (32.164 us; speedup 1.0000x reference)
//
#include <hip/hip_runtime.h>
#include <stdint.h>

// Contrastive loss: B=16384, C=1000, D=128, fp32 in, scalar fp32 out.
// dist = f2 + c2 - 2*cross; loss = sum(relu(1-dist) over j!=target)/B.
//
// Round 10: r9's closs body UNCHANGED (24.9us best: XCD row-ownership
// swizzle, 16-row waves, 4/CU, __any epilogue). Structural change only:
// the reduce node is folded into closs via per-block FLAGS (distinct
// addresses -> none of r7's same-address atomic serialization). All 1024
// blocks are co-resident (256 CU x 4/CU), so block 0 can spin: each block
// release-stores partial+flag; block 0 acquire-polls 1024 flags, reduces,
// writes out[0]. Flags zeroed by prep each call -> deterministic replay.
#define B_N 16384
#define C_N 1000
#define D_N 128
#define NB_TOT 64          // 1024 padded columns / 16
#define MARGIN 1.0f
#define NBLK 1024

typedef __attribute__((ext_vector_type(8))) short short8;  // 8 bf16
typedef __attribute__((ext_vector_type(4))) float f32x4;   // MFMA acc

__device__ __forceinline__ short f2bf(float f) {
    union { float f; uint32_t u; } v; v.f = f;
    uint32_t u = v.u;
    return (short)((u + 0x7FFFu + ((u >> 16) & 1u)) >> 16);
}

__device__ __forceinline__ short8 cvt8(const float4& v0, const float4& v1) {
    short8 s;
    s[0] = f2bf(v0.x); s[1] = f2bf(v0.y); s[2] = f2bf(v0.z); s[3] = f2bf(v0.w);
    s[4] = f2bf(v1.x); s[5] = f2bf(v1.y); s[6] = f2bf(v1.z); s[7] = f2bf(v1.w);
    return s;
}

// ---- kernel 1: cls -> bf16 fragment order + c2 (1e30 sentinel past C_N)
// + zero the 1024 completion flags. Fragment (nb,kk): lane (l15,kg) holds
// cls[nb*16+l15][kk*32+kg*8 .. +8] at shorts nb*2048 + kk*512 + lane*8.
__global__ __launch_bounds__(64) void prep_kernel(
    const float* __restrict__ cls, short* __restrict__ bpre,
    float* __restrict__ c2p, unsigned int* __restrict__ flags)
{
    const int nb   = blockIdx.x;       // 0..63
    const int lane = threadIdx.x;      // 0..63
    const int l15  = lane & 15;
    const int kg   = lane >> 4;
    const int col  = nb * 16 + l15;
    const bool valid = col < C_N;

    float sq = 0.f;
    #pragma unroll
    for (int kk = 0; kk < 4; ++kk) {
        float4 v0 = make_float4(0.f, 0.f, 0.f, 0.f);
        float4 v1 = make_float4(0.f, 0.f, 0.f, 0.f);
        if (valid) {
            const float* p = cls + (size_t)col * D_N + kk * 32 + kg * 8;
            v0 = *reinterpret_cast<const float4*>(p);
            v1 = *reinterpret_cast<const float4*>(p + 4);
        }
        sq += v0.x*v0.x + v0.y*v0.y + v0.z*v0.z + v0.w*v0.w
            + v1.x*v1.x + v1.y*v1.y + v1.z*v1.z + v1.w*v1.w;
        *reinterpret_cast<short8*>(bpre + (size_t)(nb * 2048 + kk * 512 + lane * 8))
            = cvt8(v0, v1);
    }
    sq += __shfl_xor(sq, 16);
    sq += __shfl_xor(sq, 32);
    if (lane < 16)
        c2p[nb * 16 + lane] = ((nb * 16 + lane) < C_N) ? sq : 1e30f;
    // zero this block's 16 flags (device-visible)
    if (lane < 16)
        __hip_atomic_store(&flags[nb * 16 + lane], 0u, __ATOMIC_RELAXED,
                           __HIP_MEMORY_SCOPE_AGENT);
}

// ---- kernel 2: r9 body + embedded final reduction (block 0 flag-poll) ----
__global__ __launch_bounds__(256, 4) void closs_kernel(
    const float* __restrict__ feat, const long long* __restrict__ tgt,
    const short* __restrict__ bpre, const float* __restrict__ c2p,
    float* __restrict__ part, unsigned int* __restrict__ flags,
    float* __restrict__ out)
{
    const int tid  = threadIdx.x;
    const int wave = tid >> 6;
    const int lane = tid & 63;
    const int l15  = lane & 15;
    const int kg   = lane >> 4;

    const int bid  = blockIdx.x;
    const int xcd  = bid & 7;
    const int idx  = bid >> 3;
    const int by   = (xcd << 5) | (idx >> 2);   // 0..255  row-tile (64 rows)
    const int bx   = idx & 3;                   // 0..3    col-slice (256 cols)
    const int row0 = by * 64 + wave * 16;       // wave's 16-row base
    const int nb0  = bx * 16;                   // 16 col-blocks per wave

    // ---- A fragments (16 rows x K=128) into registers + f2 on the fly ----
    short8 a[4];
    float sq = 0.f;
    const float* ap = feat + (size_t)(row0 + l15) * D_N + kg * 8;
    #pragma unroll
    for (int kk = 0; kk < 4; ++kk) {
        float4 v0 = *reinterpret_cast<const float4*>(ap + kk * 32);
        float4 v1 = *reinterpret_cast<const float4*>(ap + kk * 32 + 4);
        sq += v0.x*v0.x + v0.y*v0.y + v0.z*v0.z + v0.w*v0.w
            + v1.x*v1.x + v1.y*v1.y + v1.z*v1.z + v1.w*v1.w;
        a[kk] = cvt8(v0, v1);
    }
    sq += __shfl_xor(sq, 16);
    sq += __shfl_xor(sq, 32);
    float t[4]; int tg[4];
    #pragma unroll
    for (int r = 0; r < 4; ++r) {
        t[r]  = MARGIN - __shfl(sq, kg * 4 + r);
        tg[r] = (int)tgt[row0 + kg * 4 + r];        // int64 targets
    }

    // ---- main loop: 16 col-blocks x {4 B-frag loads, 4 MFMA, epilogue} ----
    float hsum = 0.f;
    #pragma unroll 4
    for (int i = 0; i < 16; ++i) {
        const int nb = nb0 + i;
        const short8* bp =
            reinterpret_cast<const short8*>(bpre + (size_t)nb * 2048) + lane;
        short8 b0 = bp[0];
        short8 b1 = bp[64];
        short8 b2 = bp[128];
        short8 b3 = bp[192];
        f32x4 acc = (f32x4){0.f, 0.f, 0.f, 0.f};
        acc = __builtin_amdgcn_mfma_f32_16x16x32_bf16(a[0], b0, acc, 0, 0, 0);
        acc = __builtin_amdgcn_mfma_f32_16x16x32_bf16(a[1], b1, acc, 0, 0, 0);
        acc = __builtin_amdgcn_mfma_f32_16x16x32_bf16(a[2], b2, acc, 0, 0, 0);
        acc = __builtin_amdgcn_mfma_f32_16x16x32_bf16(a[3], b3, acc, 0, 0, 0);

        // Epilogue. C/D layout (m89): col = lane&15, row = kg*4 + r.
        // u = 2*acc + (MARGIN - f2 - c2); hinge active iff u > 0 (~never).
        const int   col = nb * 16 + l15;
        const float c2v = c2p[col];     // 1e30 for padded cols -> u < 0
        float u[4];
        u[0] = __builtin_fmaf(2.0f, acc[0], t[0] - c2v);
        u[1] = __builtin_fmaf(2.0f, acc[1], t[1] - c2v);
        u[2] = __builtin_fmaf(2.0f, acc[2], t[2] - c2v);
        u[3] = __builtin_fmaf(2.0f, acc[3], t[3] - c2v);
        const float mx = fmaxf(fmaxf(u[0], u[1]), fmaxf(u[2], u[3]));
        if (__any(mx > 0.0f)) {   // wave-uniform slow path: mask + accumulate
            #pragma unroll
            for (int r = 0; r < 4; ++r)
                hsum += (col != tg[r]) ? fmaxf(0.0f, u[r]) : 0.0f;
        }
    }

    // ---- block partial + flag (distinct addresses: no serialization) ----
    #pragma unroll
    for (int off = 32; off; off >>= 1) hsum += __shfl_down(hsum, off);
    __shared__ float ws[4];
    if (lane == 0) ws[wave] = hsum;
    __syncthreads();
    if (tid == 0) {
        const float psum = ws[0] + ws[1] + ws[2] + ws[3];
        __hip_atomic_store(&part[bid], psum, __ATOMIC_RELAXED,
                           __HIP_MEMORY_SCOPE_AGENT);
        __hip_atomic_store(&flags[bid], 1u, __ATOMIC_RELEASE,
                           __HIP_MEMORY_SCOPE_AGENT);
    }

    // ---- block 0: poll all 1024 flags, then reduce partials -> out ----
    if (bid == 0) {
        #pragma unroll
        for (int i = 0; i < 4; ++i) {
            const int j = tid + i * 256;
            while (__hip_atomic_load(&flags[j], __ATOMIC_ACQUIRE,
                                     __HIP_MEMORY_SCOPE_AGENT) == 0u)
                __builtin_amdgcn_s_sleep(8);
        }
        __syncthreads();
        float s = 0.f;
        #pragma unroll
        for (int i = 0; i < 4; ++i)
            s += __hip_atomic_load(&part[tid + i * 256], __ATOMIC_RELAXED,
                                   __HIP_MEMORY_SCOPE_AGENT);
        #pragma unroll
        for (int off = 32; off; off >>= 1) s += __shfl_down(s, off);
        __shared__ float fs[4];
        if (lane == 0) fs[wave] = s;
        __syncthreads();
        if (tid == 0)
            out[0] = (fs[0] + fs[1] + fs[2] + fs[3]) * (1.0f / 16384.0f);
    }
}

extern "C" void kernel_launch(void* const* d_in, const int* in_sizes, int n_in,
                              void* d_out, int out_size, void* d_ws, size_t ws_size,
                              hipStream_t stream) {
    const float*     feat = (const float*)d_in[0];
    const long long* tgt  = (const long long*)d_in[1];   // int64 targets
    const float*     cls  = (const float*)d_in[2];
    float*           out  = (float*)d_out;

    short*        bpre  = (short*)d_ws;                                    // 256 KiB
    float*        c2p   = (float*)((char*)d_ws + 64 * 2048 * sizeof(short)); // 4 KiB
    float*        part  = c2p + 1024;                                      // 4 KiB
    unsigned int* flags = (unsigned int*)(part + NBLK);                    // 4 KiB

    prep_kernel<<<64, 64, 0, stream>>>(cls, bpre, c2p, flags);
    closs_kernel<<<NBLK, 256, 0, stream>>>(feat, tgt, bpre, c2p, part, flags, out);
}

// Round 11
// 24.298 us; speedup vs baseline: 1.3237x; 1.3237x over previous
//
#include <hip/hip_runtime.h>
#include <stdint.h>

// Contrastive loss: B=16384, C=1000, D=128, fp32 in, scalar fp32 out.
// dist = f2 + c2 - 2*cross; loss = sum(relu(1-dist) over j!=target)/B.
//
// Round 11: revert r10's flag-poll (+7us: cross-XCD release/acquire > node
// cost). r9's proven 3-node structure (24.9us best) with ONE body delta:
// explicit ILP. (a) B-fragment double-buffer prefetched BEFORE the A
// prologue (B L2 latency hides under A HBM latency), depth-2 rotation in
// the fully unrolled loop; (b) per-iteration accumulator split into two
// independent MFMA chains; (c) all 16 c2 values hoisted to registers.
// Lessons kept: no same-addr atomics (r2/r7: ~16ns serialized each), B
// converted once by prep (r6), XCD row-ownership swizzle (r9: -1.5us),
// wave-uniform __any epilogue (r8).
#define B_N 16384
#define C_N 1000
#define D_N 128
#define MARGIN 1.0f
#define NBLK 1024

typedef __attribute__((ext_vector_type(8))) short short8;  // 8 bf16
typedef __attribute__((ext_vector_type(4))) float f32x4;   // MFMA acc

__device__ __forceinline__ short f2bf(float f) {
    union { float f; uint32_t u; } v; v.f = f;
    uint32_t u = v.u;
    return (short)((u + 0x7FFFu + ((u >> 16) & 1u)) >> 16);
}

__device__ __forceinline__ short8 cvt8(const float4& v0, const float4& v1) {
    short8 s;
    s[0] = f2bf(v0.x); s[1] = f2bf(v0.y); s[2] = f2bf(v0.z); s[3] = f2bf(v0.w);
    s[4] = f2bf(v1.x); s[5] = f2bf(v1.y); s[6] = f2bf(v1.z); s[7] = f2bf(v1.w);
    return s;
}

__device__ __forceinline__ void load_bfrag(const short* __restrict__ bpre,
                                           int nb, int lane, short8* dst) {
    const short8* bp = reinterpret_cast<const short8*>(bpre + (size_t)nb * 2048) + lane;
    dst[0] = bp[0];
    dst[1] = bp[64];
    dst[2] = bp[128];
    dst[3] = bp[192];
}

// ---- kernel 1: cls -> bf16 fragment order + c2 (1e30 sentinel past C_N).
// Fragment (nb,kk): lane (l15,kg) holds cls[nb*16+l15][kk*32+kg*8 .. +8]
// at shorts nb*2048 + kk*512 + lane*8.
__global__ __launch_bounds__(64) void prep_kernel(
    const float* __restrict__ cls, short* __restrict__ bpre,
    float* __restrict__ c2p)
{
    const int nb   = blockIdx.x;       // 0..63
    const int lane = threadIdx.x;      // 0..63
    const int l15  = lane & 15;
    const int kg   = lane >> 4;
    const int col  = nb * 16 + l15;
    const bool valid = col < C_N;

    float sq = 0.f;
    #pragma unroll
    for (int kk = 0; kk < 4; ++kk) {
        float4 v0 = make_float4(0.f, 0.f, 0.f, 0.f);
        float4 v1 = make_float4(0.f, 0.f, 0.f, 0.f);
        if (valid) {
            const float* p = cls + (size_t)col * D_N + kk * 32 + kg * 8;
            v0 = *reinterpret_cast<const float4*>(p);
            v1 = *reinterpret_cast<const float4*>(p + 4);
        }
        sq += v0.x*v0.x + v0.y*v0.y + v0.z*v0.z + v0.w*v0.w
            + v1.x*v1.x + v1.y*v1.y + v1.z*v1.z + v1.w*v1.w;
        *reinterpret_cast<short8*>(bpre + (size_t)(nb * 2048 + kk * 512 + lane * 8))
            = cvt8(v0, v1);
    }
    sq += __shfl_xor(sq, 16);
    sq += __shfl_xor(sq, 32);
    if (lane < 16)
        c2p[nb * 16 + lane] = ((nb * 16 + lane) < C_N) ? sq : 1e30f;
}

// ---- kernel 2: XCD row-ownership swizzle + ILP-plumbed body ----
// 1024 blocks; xcd = bid&7 owns row-tiles [xcd*32, xcd*32+32) x 4 col-slices.
__global__ __launch_bounds__(256, 4) void closs_kernel(
    const float* __restrict__ feat, const long long* __restrict__ tgt,
    const short* __restrict__ bpre, const float* __restrict__ c2p,
    float* __restrict__ part)
{
    const int tid  = threadIdx.x;
    const int wave = tid >> 6;
    const int lane = tid & 63;
    const int l15  = lane & 15;
    const int kg   = lane >> 4;

    const int bid  = blockIdx.x;
    const int xcd  = bid & 7;
    const int idx  = bid >> 3;
    const int by   = (xcd << 5) | (idx >> 2);   // 0..255  row-tile (64 rows)
    const int bx   = idx & 3;                   // 0..3    col-slice (256 cols)
    const int row0 = by * 64 + wave * 16;       // wave's 16-row base
    const int nb0  = bx * 16;                   // 16 col-blocks per wave

    // ---- B prefetch (iter 0,1) FIRST: L2 latency hides under A's HBM ----
    short8 b0[4], b1[4];
    load_bfrag(bpre, nb0 + 0, lane, b0);
    load_bfrag(bpre, nb0 + 1, lane, b1);

    // ---- c2 for this lane's 16 columns, hoisted ----
    float c2r[16];
    #pragma unroll
    for (int i = 0; i < 16; ++i) c2r[i] = c2p[(nb0 + i) * 16 + l15];

    // ---- A fragments (16 rows x K=128) into registers + f2 on the fly ----
    short8 a[4];
    float sq = 0.f;
    const float* ap = feat + (size_t)(row0 + l15) * D_N + kg * 8;
    #pragma unroll
    for (int kk = 0; kk < 4; ++kk) {
        float4 v0 = *reinterpret_cast<const float4*>(ap + kk * 32);
        float4 v1 = *reinterpret_cast<const float4*>(ap + kk * 32 + 4);
        sq += v0.x*v0.x + v0.y*v0.y + v0.z*v0.z + v0.w*v0.w
            + v1.x*v1.x + v1.y*v1.y + v1.z*v1.z + v1.w*v1.w;
        a[kk] = cvt8(v0, v1);
    }
    sq += __shfl_xor(sq, 16);
    sq += __shfl_xor(sq, 32);
    float t[4]; int tg[4];
    #pragma unroll
    for (int r = 0; r < 4; ++r) {
        t[r]  = MARGIN - __shfl(sq, kg * 4 + r);
        tg[r] = (int)tgt[row0 + kg * 4 + r];        // int64 targets
    }

    // ---- main loop: fully unrolled, depth-2 B rotation, 2 MFMA chains ----
    float hsum = 0.f;
    #pragma unroll
    for (int i = 0; i < 16; ++i) {
        short8* bc = (i & 1) ? b1 : b0;   // static under full unroll
        f32x4 pA = (f32x4){0.f, 0.f, 0.f, 0.f};
        f32x4 pB = (f32x4){0.f, 0.f, 0.f, 0.f};
        pA = __builtin_amdgcn_mfma_f32_16x16x32_bf16(a[0], bc[0], pA, 0, 0, 0);
        pB = __builtin_amdgcn_mfma_f32_16x16x32_bf16(a[1], bc[1], pB, 0, 0, 0);
        pA = __builtin_amdgcn_mfma_f32_16x16x32_bf16(a[2], bc[2], pA, 0, 0, 0);
        pB = __builtin_amdgcn_mfma_f32_16x16x32_bf16(a[3], bc[3], pB, 0, 0, 0);
        if (i + 2 < 16)                    // refill consumed buffer (depth 2)
            load_bfrag(bpre, nb0 + i + 2, lane, bc);

        // Epilogue. C/D layout (m89): col = lane&15, row = kg*4 + r.
        // u = 2*(pA+pB) + (MARGIN - f2 - c2); hinge active iff u > 0 (~never).
        const float c2v = c2r[i];
        float u[4];
        #pragma unroll
        for (int r = 0; r < 4; ++r)
            u[r] = __builtin_fmaf(2.0f, pA[r] + pB[r], t[r] - c2v);
        const float mx = fmaxf(fmaxf(u[0], u[1]), fmaxf(u[2], u[3]));
        if (__any(mx > 0.0f)) {   // wave-uniform slow path: mask + accumulate
            const int col = (nb0 + i) * 16 + l15;
            #pragma unroll
            for (int r = 0; r < 4; ++r)
                hsum += (col != tg[r]) ? fmaxf(0.0f, u[r]) : 0.0f;
        }
    }

    // ---- reduce: wave -> block -> plain store (no contended atomics) ----
    #pragma unroll
    for (int off = 32; off; off >>= 1) hsum += __shfl_down(hsum, off);
    __shared__ float ws[4];
    if (lane == 0) ws[wave] = hsum;
    __syncthreads();
    if (tid == 0)
        part[bid] = ws[0] + ws[1] + ws[2] + ws[3];
}

// ---- kernel 3: reduce 1024 partials -> out[0] ----
__global__ __launch_bounds__(256) void reduce_kernel(
    const float* __restrict__ part, float* __restrict__ out)
{
    const int tid = threadIdx.x;
    float s = part[tid] + part[tid + 256] + part[tid + 512] + part[tid + 768];
    #pragma unroll
    for (int off = 32; off; off >>= 1) s += __shfl_down(s, off);
    __shared__ float ws[4];
    if ((tid & 63) == 0) ws[tid >> 6] = s;
    __syncthreads();
    if (tid == 0) out[0] = (ws[0] + ws[1] + ws[2] + ws[3]) * (1.0f / 16384.0f);
}

extern "C" void kernel_launch(void* const* d_in, const int* in_sizes, int n_in,
                              void* d_out, int out_size, void* d_ws, size_t ws_size,
                              hipStream_t stream) {
    const float*     feat = (const float*)d_in[0];
    const long long* tgt  = (const long long*)d_in[1];   // int64 targets
    const float*     cls  = (const float*)d_in[2];
    float*           out  = (float*)d_out;

    short* bpre = (short*)d_ws;                                      // 256 KiB
    float* c2p  = (float*)((char*)d_ws + 64 * 2048 * sizeof(short)); // 4 KiB
    float* part = c2p + 1024;                                        // 4 KiB

    prep_kernel<<<64, 64, 0, stream>>>(cls, bpre, c2p);
    closs_kernel<<<NBLK, 256, 0, stream>>>(feat, tgt, bpre, c2p, part);
    reduce_kernel<<<1, 256, 0, stream>>>(part, out);
}